// Round 5
// baseline (721.788 us; speedup 1.0000x reference)
//
#include <hip/hip_runtime.h>
#include <math.h>

// VQ via split-fp16 MFMA emulation of fp32 GEMM.
// Round 5: B fragments loaded DIRECTLY from pre-permuted global W into VGPRs
// (no Bsh LDS, no global_load_lds, NO barriers in the main loop — waves free-run).
// x [32,256,32,32] f32, codebook [8192,256] f32.
// d2 = (||f||^2 - 2 f.c) + ||c||^2, argmin over 8192 codes, np association.
// f.c = 2^-26 * MFMA(h/m split of 8192*f, 8192*c): products hh+hm+mh.
// Outputs: codes [32,256,32,32] f32 then indices [32,32,32] (as float).

typedef _Float16 v8h __attribute__((ext_vector_type(8)));
typedef float f32x16 __attribute__((ext_vector_type(16)));
typedef unsigned int u32;

#define MFMA16 __builtin_amdgcn_mfma_f32_32x32x16_f16

__global__ __launch_bounds__(256) void cnorm_k(const float4* __restrict__ cb4,
                                               float* __restrict__ cn) {
  int lane = threadIdx.x & 63;
  int row = (blockIdx.x << 2) + (threadIdx.x >> 6);
  float4 v = cb4[(size_t)row * 64 + lane];
  float s = v.x * v.x + v.y * v.y + v.z * v.z + v.w * v.w;
#pragma unroll
  for (int off = 32; off > 0; off >>= 1) s += __shfl_xor(s, off, 64);
  if (lane == 0) cn[row] = s;
}

// Pre-split codebook into h/m fp16 planes, permuted so each (ct,ks) 32KB tile is
// the exact per-lane fragment image: halves[((pl*2+hi)*512 + code)*8 + i],
// value = plane of 8192*cb[ct*512+code][ks*16+hi*8+i].
__global__ __launch_bounds__(256) void split_cb(const float4* __restrict__ cb4,
                                                _Float16* __restrict__ W) {
  const int j = threadIdx.x & 31;
  const int ks = j >> 1, hi = j & 1;
  const int r = (blockIdx.x << 3) + (threadIdx.x >> 5);  // code row 0..8191
  const float4* src = cb4 + (size_t)r * 64 + (ks << 2) + (hi << 1);
  float4 v0 = src[0], v1 = src[1];
  float t[8] = {v0.x, v0.y, v0.z, v0.w, v1.x, v1.y, v1.z, v1.w};
  v8h hv, mv;
#pragma unroll
  for (int i = 0; i < 8; ++i) {
    float vs = t[i] * 8192.f;
    _Float16 h = (_Float16)vs;
    _Float16 m = (_Float16)(vs - (float)h);
    hv[i] = h; mv[i] = m;
  }
  const int code = r & 511;
  _Float16* base = W + ((size_t)((r >> 9) << 4) + ks) * 16384;  // tile = ct*16+ks
  *(v8h*)(base + (((hi << 9) + code) << 3)) = hv;                // pl=0
  *(v8h*)(base + ((1024 + (hi << 9) + code) << 3)) = mv;         // pl=1
}

__global__ void __launch_bounds__(512, 1) vq_fast(const float* __restrict__ x,
                                                  const float4* __restrict__ cb4,
                                                  const float* __restrict__ cn,
                                                  const _Float16* __restrict__ W,
                                                  float* __restrict__ out) {
  __shared__ __align__(16) _Float16 F2[2][64][264];   // 67,584 B: -2x splits, padded
  __shared__ float fnP[64][8];
  __shared__ float fnS[64];
  __shared__ float wredS[8][64];
  __shared__ u32  wredC[8][64];
  __shared__ u32  finS[64];

  const int tid = threadIdx.x;
  const int lane = tid & 63;
  const int w = tid >> 6;
  const int col = lane & 31;
  const int hi = lane >> 5;
  const int b = blockIdx.x >> 4;
  const int h0 = (blockIdx.x & 15) << 1;

  // per-lane B-fragment base offset within a 16384-half tile:
  // bh0 = (hi*512 + w*64 + col)*8 ; bh1 = +256 ; bm0 = +8192 ; bm1 = +8448
  const int boff = (((hi << 9) + (w << 6) + col) << 3);

  // ---- prologue B loads for st=0 (overlap with F staging)
  v8h Bh0[2], Bh1[2], Bm0[2], Bm1[2];
  {
    const _Float16* q = W + boff;
    Bh0[0] = *(const v8h*)(q);
    Bh1[0] = *(const v8h*)(q + 256);
    Bm0[0] = *(const v8h*)(q + 8192);
    Bm1[0] = *(const v8h*)(q + 8448);
  }

  // ---- stage F splits (scaled by 2^13) + fn partials
  {
    const float* xb = x + ((size_t)b << 18) + (h0 << 5);
    float s = 0.f;
#pragma unroll
    for (int j = 0; j < 4; ++j) {
      v8h hv, mv;
#pragma unroll
      for (int i = 0; i < 8; ++i) {
        const int c = (w << 5) + (j << 3) + i;
        float v = xb[(size_t)c * 1024 + lane];   // coalesced: lane = point
        s += v * v;
        float vs = v * 8192.f;
        _Float16 h = (_Float16)vs;
        _Float16 m = (_Float16)(vs - (float)h);
        hv[i] = h; mv[i] = m;
      }
      *(v8h*)&F2[0][lane][(w << 5) + (j << 3)] = hv;
      *(v8h*)&F2[1][lane][(w << 5) + (j << 3)] = mv;
    }
    fnP[lane][w] = s;
  }
  __syncthreads();   // F2 + fnP visible
  if (tid < 64) {
    float t = 0.f;
#pragma unroll
    for (int j = 0; j < 8; ++j) t += fnP[tid][j];
    fnS[tid] = t;
  }
  __syncthreads();   // fnS visible — LAST barrier before the epilogue reductions

  // ---- prologue A reads for ks=0
  v8h Ah0[2], Ah1[2], Am0[2], Am1[2];
  {
    const int ko = (hi << 3);
    Ah0[0] = *(const v8h*)&F2[0][col][ko];
    Ah1[0] = *(const v8h*)&F2[0][32 + col][ko];
    Am0[0] = *(const v8h*)&F2[1][col][ko];
    Am1[0] = *(const v8h*)&F2[1][32 + col][ko];
  }

  f32x16 a00, a01, a10, a11;
#pragma unroll
  for (int r = 0; r < 16; ++r) { a00[r] = 0.f; a01[r] = 0.f; a10[r] = 0.f; a11[r] = 0.f; }
  float mn[32];
#pragma unroll
  for (int sl = 0; sl < 32; ++sl) mn[sl] = INFINITY;
  u32 idp[8] = {0, 0, 0, 0, 0, 0, 0, 0};

  // ---- main loop: 16 code tiles x 16 k-steps, fully barrier-free
  for (int ct = 0; ct < 16; ++ct) {
    const float cnv0 = cn[(ct << 9) + (w << 6) + col];        // used ~16 steps later
    const float cnv1 = cn[(ct << 9) + (w << 6) + 32 + col];
#pragma unroll
    for (int ks = 0; ks < 16; ++ks) {
      const int p = ks & 1, n = p ^ 1;
      // depth-1 prefetch of next step's B (global, L2-hot) and A (LDS)
      if (ks < 15 || ct < 15) {
        const int stn = (ct << 4) + ks + 1;
        const _Float16* q = W + ((size_t)stn << 14) + boff;
        Bh0[n] = *(const v8h*)(q);
        Bh1[n] = *(const v8h*)(q + 256);
        Bm0[n] = *(const v8h*)(q + 8192);
        Bm1[n] = *(const v8h*)(q + 8448);
        const int ko = (((ks + 1) & 15) << 4) + (hi << 3);
        Ah0[n] = *(const v8h*)&F2[0][col][ko];
        Ah1[n] = *(const v8h*)&F2[0][32 + col][ko];
        Am0[n] = *(const v8h*)&F2[1][col][ko];
        Am1[n] = *(const v8h*)&F2[1][32 + col][ko];
      }
      // 12 MFMAs, round-robin across the 4 acc chains (dep distance 4)
      a00 = MFMA16(Ah0[p], Bh0[p], a00, 0, 0, 0);
      a01 = MFMA16(Ah0[p], Bh1[p], a01, 0, 0, 0);
      a10 = MFMA16(Ah1[p], Bh0[p], a10, 0, 0, 0);
      a11 = MFMA16(Ah1[p], Bh1[p], a11, 0, 0, 0);
      a00 = MFMA16(Ah0[p], Bm0[p], a00, 0, 0, 0);
      a01 = MFMA16(Ah0[p], Bm1[p], a01, 0, 0, 0);
      a10 = MFMA16(Ah1[p], Bm0[p], a10, 0, 0, 0);
      a11 = MFMA16(Ah1[p], Bm1[p], a11, 0, 0, 0);
      a00 = MFMA16(Am0[p], Bh0[p], a00, 0, 0, 0);
      a01 = MFMA16(Am0[p], Bh1[p], a01, 0, 0, 0);
      a10 = MFMA16(Am1[p], Bh0[p], a10, 0, 0, 0);
      a11 = MFMA16(Am1[p], Bh1[p], a11, 0, 0, 0);
    }
    // ---- tile epilogue: s = (fn - 2*dot) + cn, running argmin
#pragma unroll
    for (int sl = 0; sl < 32; ++sl) {
      const int Mb = sl >> 4, reg = sl & 15;
      const int row = ((sl >> 4) << 5) + (sl & 3) + (((sl >> 2) & 3) << 3) + (hi << 2);
      const float base = fnS[row];
      const u32 sh = (u32)((sl & 3) << 3);
      const float d0 = (Mb == 0) ? a00[reg] : a10[reg];
      const float d1 = (Mb == 0) ? a01[reg] : a11[reg];
      {
        float s = (base + (-0x1p-25f) * d0) + cnv0;
        const bool better = s < mn[sl];
        const u32 curv = idp[sl >> 2];
        const u32 upd = (curv & ~(255u << sh)) | (((u32)(ct << 1)) << sh);
        idp[sl >> 2] = better ? upd : curv;
        mn[sl] = better ? s : mn[sl];
      }
      {
        float s = (base + (-0x1p-25f) * d1) + cnv1;
        const bool better = s < mn[sl];
        const u32 curv = idp[sl >> 2];
        const u32 upd = (curv & ~(255u << sh)) | (((u32)((ct << 1) | 1)) << sh);
        idp[sl >> 2] = better ? upd : curv;
        mn[sl] = better ? s : mn[sl];
      }
    }
#pragma unroll
    for (int r = 0; r < 16; ++r) { a00[r] = 0.f; a01[r] = 0.f; a10[r] = 0.f; a11[r] = 0.f; }
  }

  // ---- final reduction: per-slot butterfly over 32 col-lanes, then cross-wave
#pragma unroll
  for (int sl = 0; sl < 32; ++sl) {
    float v = mn[sl];
    const u32 byte = (idp[sl >> 2] >> ((sl & 3) << 3)) & 255u;
    u32 code = ((byte >> 1) << 9) + ((u32)w << 6) + ((byte & 1) << 5) + (u32)col;
#pragma unroll
    for (int off = 1; off < 32; off <<= 1) {
      float v2 = __shfl_xor(v, off, 64);
      u32 c2 = (u32)__shfl_xor((int)code, off, 64);
      if (v2 < v || (v2 == v && c2 < code)) { v = v2; code = c2; }
    }
    if (col == 0) {
      const int row = ((sl >> 4) << 5) + (sl & 3) + (((sl >> 2) & 3) << 3) + (hi << 2);
      wredS[w][row] = v; wredC[w][row] = code;
    }
  }
  __syncthreads();
  if (tid < 64) {
    float bv = wredS[0][tid]; u32 bc = wredC[0][tid];
#pragma unroll
    for (int j = 1; j < 8; ++j) {
      float vv = wredS[j][tid]; u32 cc = wredC[j][tid];
      if (vv < bv || (vv == bv && cc < bc)) { bv = vv; bc = cc; }
    }
    finS[tid] = bc;
    out[(size_t)8388608 + ((size_t)b << 10) + (h0 << 5) + tid] = (float)bc;
  }
  __syncthreads();

  // ---- codes gather: out[b,c,h,w] = codebook[idx][c]
  {
    const int pt = tid & 63, cg = tid >> 6;
    const u32 code = finS[pt];
    const float4* cbr = cb4 + ((size_t)code << 6);
    const size_t obase = ((size_t)b << 18) + (h0 << 5) + pt;
#pragma unroll
    for (int cc = 0; cc < 8; ++cc) {
      const int c4 = (cc << 3) + cg;
      float4 vv = cbr[c4];
      out[obase + (size_t)((c4 << 2) + 0) * 1024] = vv.x;
      out[obase + (size_t)((c4 << 2) + 1) * 1024] = vv.y;
      out[obase + (size_t)((c4 << 2) + 2) * 1024] = vv.z;
      out[obase + (size_t)((c4 << 2) + 3) * 1024] = vv.w;
    }
  }
}

// ---------------- fallback (round-3 kernel, used only if ws too small) -------
__global__ void __launch_bounds__(512, 2) vq_fb(const float* __restrict__ x,
                                                const float4* __restrict__ cb4,
                                                const float* __restrict__ cn,
                                                float* __restrict__ out) {
  __shared__ __align__(16) _Float16 F2[2][64][264];
  __shared__ __align__(16) _Float16 Bsh[512][72];
  __shared__ float fnP[64][8];
  __shared__ float fnS[64];
  __shared__ float wredS[8][64];
  __shared__ u32  wredC[8][64];
  __shared__ u32  finS[64];

  const int tid = threadIdx.x;
  const int lane = tid & 63;
  const int w = tid >> 6;
  const int col = lane & 31;
  const int hi = lane >> 5;
  const int b = blockIdx.x >> 4;
  const int h0 = (blockIdx.x & 15) << 1;

  float4 rg[8];
  {
    const float4* src = cb4 + ((size_t)tid << 6);
#pragma unroll
    for (int j = 0; j < 8; ++j) rg[j] = src[j];
  }
  {
    const float* xb = x + ((size_t)b << 18) + (h0 << 5);
    float s = 0.f;
#pragma unroll
    for (int j = 0; j < 4; ++j) {
      v8h hv, mv;
#pragma unroll
      for (int i = 0; i < 8; ++i) {
        const int c = (w << 5) + (j << 3) + i;
        float v = xb[(size_t)c * 1024 + lane];
        s += v * v;
        float vs = v * 8192.f;
        _Float16 h = (_Float16)vs;
        _Float16 m = (_Float16)(vs - (float)h);
        hv[i] = h; mv[i] = m;
      }
      *(v8h*)&F2[0][lane][(w << 5) + (j << 3)] = hv;
      *(v8h*)&F2[1][lane][(w << 5) + (j << 3)] = mv;
    }
    fnP[lane][w] = s;
  }
  __syncthreads();
  if (tid < 64) {
    float t = 0.f;
#pragma unroll
    for (int j = 0; j < 8; ++j) t += fnP[tid][j];
    fnS[tid] = t;
  }
  {
#pragma unroll
    for (int j = 0; j < 4; ++j) {
      float t0[8] = {rg[2*j].x, rg[2*j].y, rg[2*j].z, rg[2*j].w,
                     rg[2*j+1].x, rg[2*j+1].y, rg[2*j+1].z, rg[2*j+1].w};
      v8h hv, mv;
#pragma unroll
      for (int i = 0; i < 8; ++i) {
        float vs = t0[i] * 8192.f;
        _Float16 h = (_Float16)vs;
        _Float16 m = (_Float16)(vs - (float)h);
        hv[i] = h; mv[i] = m;
      }
      *(v8h*)&Bsh[tid][(j << 3)] = hv;
      *(v8h*)&Bsh[tid][32 + (j << 3)] = mv;
    }
  }
  __syncthreads();

  float fnr[32];
#pragma unroll
  for (int sl = 0; sl < 32; ++sl) {
    const int row = ((sl >> 4) << 5) + (sl & 3) + (((sl >> 2) & 3) << 3) + (hi << 2);
    fnr[sl] = fnS[row];
  }

  f32x16 acc[2][2];
#pragma unroll
  for (int r = 0; r < 16; ++r) {
    acc[0][0][r] = 0.f; acc[0][1][r] = 0.f; acc[1][0][r] = 0.f; acc[1][1][r] = 0.f;
  }
  float mn[32];
#pragma unroll
  for (int sl = 0; sl < 32; ++sl) mn[sl] = INFINITY;
  u32 idp[8] = {0, 0, 0, 0, 0, 0, 0, 0};
  float cnv0 = 0.f, cnv1 = 0.f;

  for (int st = 0; st < 128; ++st) {
    const int ks = st & 7, ct = st >> 3;
    if (st < 127) {
      const int tn = st + 1;
      const float4* src = cb4 + ((size_t)((((tn >> 3) << 9) + tid)) << 6) + ((tn & 7) << 3);
#pragma unroll
      for (int j = 0; j < 8; ++j) rg[j] = src[j];
    }
    if (ks == 0) {
      cnv0 = cn[(ct << 9) + (w << 6) + col];
      cnv1 = cn[(ct << 9) + (w << 6) + 32 + col];
    }
    const int kb = ks << 5;
#pragma unroll
    for (int kh = 0; kh < 2; ++kh) {
      const int ko = kb + (kh << 4) + (hi << 3);
      const v8h ah0 = *(const v8h*)&F2[0][col][ko];
      const v8h ah1 = *(const v8h*)&F2[0][32 + col][ko];
      const v8h am0 = *(const v8h*)&F2[1][col][ko];
      const v8h am1 = *(const v8h*)&F2[1][32 + col][ko];
      const int bo = (kh << 4) + (hi << 3);
      const v8h bh0 = *(const v8h*)&Bsh[(w << 6) + col][bo];
      const v8h bh1 = *(const v8h*)&Bsh[(w << 6) + 32 + col][bo];
      const v8h bm0 = *(const v8h*)&Bsh[(w << 6) + col][32 + bo];
      const v8h bm1 = *(const v8h*)&Bsh[(w << 6) + 32 + col][32 + bo];
      acc[0][0] = MFMA16(ah0, bh0, acc[0][0], 0, 0, 0);
      acc[0][0] = MFMA16(ah0, bm0, acc[0][0], 0, 0, 0);
      acc[0][0] = MFMA16(am0, bh0, acc[0][0], 0, 0, 0);
      acc[0][1] = MFMA16(ah0, bh1, acc[0][1], 0, 0, 0);
      acc[0][1] = MFMA16(ah0, bm1, acc[0][1], 0, 0, 0);
      acc[0][1] = MFMA16(am0, bh1, acc[0][1], 0, 0, 0);
      acc[1][0] = MFMA16(ah1, bh0, acc[1][0], 0, 0, 0);
      acc[1][0] = MFMA16(ah1, bm0, acc[1][0], 0, 0, 0);
      acc[1][0] = MFMA16(am1, bh0, acc[1][0], 0, 0, 0);
      acc[1][1] = MFMA16(ah1, bh1, acc[1][1], 0, 0, 0);
      acc[1][1] = MFMA16(ah1, bm1, acc[1][1], 0, 0, 0);
      acc[1][1] = MFMA16(am1, bh1, acc[1][1], 0, 0, 0);
    }
    if (ks == 7) {
#pragma unroll
      for (int sl = 0; sl < 32; ++sl) {
        const int Mb = sl >> 4, reg = sl & 15;
        const float base = fnr[sl];
        const u32 sh = (u32)((sl & 3) << 3);
        {
          float s = (base + (-0x1p-25f) * acc[Mb][0][reg]) + cnv0;
          const bool better = s < mn[sl];
          const u32 curv = idp[sl >> 2];
          const u32 upd = (curv & ~(255u << sh)) | (((u32)(ct << 1)) << sh);
          idp[sl >> 2] = better ? upd : curv;
          mn[sl] = better ? s : mn[sl];
        }
        {
          float s = (base + (-0x1p-25f) * acc[Mb][1][reg]) + cnv1;
          const bool better = s < mn[sl];
          const u32 curv = idp[sl >> 2];
          const u32 upd = (curv & ~(255u << sh)) | (((u32)((ct << 1) | 1)) << sh);
          idp[sl >> 2] = better ? upd : curv;
          mn[sl] = better ? s : mn[sl];
        }
      }
#pragma unroll
      for (int r = 0; r < 16; ++r) {
        acc[0][0][r] = 0.f; acc[0][1][r] = 0.f; acc[1][0][r] = 0.f; acc[1][1][r] = 0.f;
      }
    }
    v8h cr[8];
    if (st < 127) {
#pragma unroll
      for (int j = 0; j < 4; ++j) {
        float t0[8] = {rg[2*j].x, rg[2*j].y, rg[2*j].z, rg[2*j].w,
                       rg[2*j+1].x, rg[2*j+1].y, rg[2*j+1].z, rg[2*j+1].w};
#pragma unroll
        for (int i = 0; i < 8; ++i) {
          float vs = t0[i] * 8192.f;
          _Float16 h = (_Float16)vs;
          _Float16 m = (_Float16)(vs - (float)h);
          cr[j][i] = h; cr[4 + j][i] = m;
        }
      }
    }
    __syncthreads();
    if (st < 127) {
#pragma unroll
      for (int j = 0; j < 4; ++j) {
        *(v8h*)&Bsh[tid][(j << 3)] = cr[j];
        *(v8h*)&Bsh[tid][32 + (j << 3)] = cr[4 + j];
      }
    }
    __syncthreads();
  }

#pragma unroll
  for (int sl = 0; sl < 32; ++sl) {
    float v = mn[sl];
    const u32 byte = (idp[sl >> 2] >> ((sl & 3) << 3)) & 255u;
    u32 code = ((byte >> 1) << 9) + ((u32)w << 6) + ((byte & 1) << 5) + (u32)col;
#pragma unroll
    for (int off = 1; off < 32; off <<= 1) {
      float v2 = __shfl_xor(v, off, 64);
      u32 c2 = (u32)__shfl_xor((int)code, off, 64);
      if (v2 < v || (v2 == v && c2 < code)) { v = v2; code = c2; }
    }
    if (col == 0) {
      const int row = ((sl >> 4) << 5) + (sl & 3) + (((sl >> 2) & 3) << 3) + (hi << 2);
      wredS[w][row] = v; wredC[w][row] = code;
    }
  }
  __syncthreads();
  if (tid < 64) {
    float bv = wredS[0][tid]; u32 bc = wredC[0][tid];
#pragma unroll
    for (int j = 1; j < 8; ++j) {
      float vv = wredS[j][tid]; u32 cc = wredC[j][tid];
      if (vv < bv || (vv == bv && cc < bc)) { bv = vv; bc = cc; }
    }
    finS[tid] = bc;
    out[(size_t)8388608 + ((size_t)b << 10) + (h0 << 5) + tid] = (float)bc;
  }
  __syncthreads();
  {
    const int pt = tid & 63, cg = tid >> 6;
    const u32 code = finS[pt];
    const float4* cbr = cb4 + ((size_t)code << 6);
    const size_t obase = ((size_t)b << 18) + (h0 << 5) + pt;
#pragma unroll
    for (int cc = 0; cc < 8; ++cc) {
      const int c4 = (cc << 3) + cg;
      float4 vv = cbr[c4];
      out[obase + (size_t)((c4 << 2) + 0) * 1024] = vv.x;
      out[obase + (size_t)((c4 << 2) + 1) * 1024] = vv.y;
      out[obase + (size_t)((c4 << 2) + 2) * 1024] = vv.z;
      out[obase + (size_t)((c4 << 2) + 3) * 1024] = vv.w;
    }
  }
}

extern "C" void kernel_launch(void* const* d_in, const int* in_sizes, int n_in,
                              void* d_out, int out_size, void* d_ws, size_t ws_size,
                              hipStream_t stream) {
  const float* x = (const float*)d_in[0];
  const float* cb = (const float*)d_in[1];
  float* out = (float*)d_out;
  float* cnorm = (float*)d_ws;  // 8192 floats at ws[0:32KB)

  cnorm_k<<<2048, 256, 0, stream>>>((const float4*)cb, cnorm);
  if (ws_size >= (size_t)32768 + (size_t)16777216) {
    _Float16* W = (_Float16*)((char*)d_ws + 32768);  // 16 MB split-permuted planes
    split_cb<<<1024, 256, 0, stream>>>((const float4*)cb, W);
    vq_fast<<<512, 512, 0, stream>>>(x, (const float4*)cb, cnorm, W, out);
  } else {
    vq_fb<<<512, 512, 0, stream>>>(x, (const float4*)cb, cnorm, out);
  }
}

// Round 6
// 441.123 us; speedup vs baseline: 1.6363x; 1.6363x over previous
//
#include <hip/hip_runtime.h>
#include <math.h>

// VQ via split-fp16 MFMA emulation of fp32 GEMM.
// Round 6: W re-permuted so each wave's staged B chunk is per-wave-PRIVATE ->
// main loop has NO barriers; sync is a counted s_waitcnt vmcnt(4) per step
// (stage(st+1) stays in flight). B staging still via global_load_lds (no VGPR
// cost, no spills). MFMA inputs bit-identical to round 4.
// x [32,256,32,32] f32, codebook [8192,256] f32.
// d2 = (||f||^2 - 2 f.c) + ||c||^2, argmin over 8192 codes, np association.
// f.c = 2^-26 * MFMA(h/m split of 8192*f, 8192*c): products hh+hm+mh.
// Outputs: codes [32,256,32,32] f32 then indices [32,32,32] (as float).

typedef _Float16 v8h __attribute__((ext_vector_type(8)));
typedef float f32x16 __attribute__((ext_vector_type(16)));
typedef unsigned int u32;

#define MFMA16 __builtin_amdgcn_mfma_f32_32x32x16_f16

__device__ __forceinline__ void gll16(const _Float16* g, _Float16* l) {
  __builtin_amdgcn_global_load_lds(
      (const __attribute__((address_space(1))) void*)(const void*)g,
      (__attribute__((address_space(3))) void*)(void*)l, 16, 0, 0);
}

__global__ __launch_bounds__(256) void cnorm_k(const float4* __restrict__ cb4,
                                               float* __restrict__ cn) {
  int lane = threadIdx.x & 63;
  int row = (blockIdx.x << 2) + (threadIdx.x >> 6);
  float4 v = cb4[(size_t)row * 64 + lane];
  float s = v.x * v.x + v.y * v.y + v.z * v.z + v.w * v.w;
#pragma unroll
  for (int off = 32; off > 0; off >>= 1) s += __shfl_xor(s, off, 64);
  if (lane == 0) cn[row] = s;
}

// Pre-split codebook into h/m fp16 planes. Tile (ct,ks) = 16384 halves laid out
// [w(8)][pl(2)][hi(2)][c64(64)][8]: wave chunk = 2048 halves, per-wave private.
// value = plane of 8192*cb[ct*512 + w*64 + c64][ks*16 + hi*8 + i].
__global__ __launch_bounds__(256) void split_cb(const float4* __restrict__ cb4,
                                                _Float16* __restrict__ W) {
  const int j = threadIdx.x & 31;
  const int ks = j >> 1, hi = j & 1;
  const int r = (blockIdx.x << 3) + (threadIdx.x >> 5);  // code row 0..8191
  const float4* src = cb4 + (size_t)r * 64 + (ks << 2) + (hi << 1);
  float4 v0 = src[0], v1 = src[1];
  float t[8] = {v0.x, v0.y, v0.z, v0.w, v1.x, v1.y, v1.z, v1.w};
  v8h hv, mv;
#pragma unroll
  for (int i = 0; i < 8; ++i) {
    float vs = t[i] * 8192.f;
    _Float16 h = (_Float16)vs;
    _Float16 m = (_Float16)(vs - (float)h);
    hv[i] = h; mv[i] = m;
  }
  const int wv = (r >> 6) & 7, c64 = r & 63;
  _Float16* base = W + ((size_t)((r >> 9) << 4) + ks) * 16384 + (wv << 11);
  *(v8h*)(base + (hi << 9) + (c64 << 3)) = hv;           // pl=0
  *(v8h*)(base + 1024 + (hi << 9) + (c64 << 3)) = mv;    // pl=1
}

__global__ void __launch_bounds__(512, 1) vq_fast(const float* __restrict__ x,
                                                  const float4* __restrict__ cb4,
                                                  const float* __restrict__ cn,
                                                  const _Float16* __restrict__ W,
                                                  float* __restrict__ out) {
  __shared__ __align__(16) _Float16 F2[2][64][264];   // 67,584 B: -2x splits, padded
  __shared__ __align__(16) _Float16 Bsh[2][16384];    // 65,536 B: dbuf, per-wave chunks
  __shared__ float fnP[64][8];
  __shared__ float fnS[64];
  __shared__ float wredS[8][64];
  __shared__ u32  wredC[8][64];
  __shared__ u32  finS[64];

  const int tid = threadIdx.x;
  const int lane = tid & 63;
  const int w = tid >> 6;
  const int col = lane & 31;
  const int hi = lane >> 5;
  const int b = blockIdx.x >> 4;
  const int h0 = (blockIdx.x & 15) << 1;

  const int chunk = w << 11;                     // wave chunk base (halves)
  const int rb0 = chunk + (hi << 9) + (col << 3);  // bh0 read offset
  // bh1 = rb0+256 ; bm0 = rb0+1024 ; bm1 = rb0+1280

  // ---- prologue: stage tile 0 into this wave's Bsh[0] chunk
  {
    const _Float16* src = W + chunk + (lane << 3);
#pragma unroll
    for (int i = 0; i < 4; ++i) gll16(src + (i << 9), &Bsh[0][chunk + (i << 9)]);
  }

  // ---- stage F splits (scaled by 2^13) + fn partials
  {
    const float* xb = x + ((size_t)b << 18) + (h0 << 5);
    float s = 0.f;
#pragma unroll
    for (int j = 0; j < 4; ++j) {
      v8h hv, mv;
#pragma unroll
      for (int i = 0; i < 8; ++i) {
        const int c = (w << 5) + (j << 3) + i;
        float v = xb[(size_t)c * 1024 + lane];   // coalesced: lane = point
        s += v * v;
        float vs = v * 8192.f;
        _Float16 h = (_Float16)vs;
        _Float16 m = (_Float16)(vs - (float)h);
        hv[i] = h; mv[i] = m;
      }
      *(v8h*)&F2[0][lane][(w << 5) + (j << 3)] = hv;
      *(v8h*)&F2[1][lane][(w << 5) + (j << 3)] = mv;
    }
    fnP[lane][w] = s;
  }
  __syncthreads();   // F2 + fnP visible
  if (tid < 64) {
    float t = 0.f;
#pragma unroll
    for (int j = 0; j < 8; ++j) t += fnP[tid][j];
    fnS[tid] = t;
  }
  __syncthreads();   // fnS visible — last barrier before the final reductions

  float fnr[32];
#pragma unroll
  for (int sl = 0; sl < 32; ++sl) {
    const int row = ((sl >> 4) << 5) + (sl & 3) + (((sl >> 2) & 3) << 3) + (hi << 2);
    fnr[sl] = fnS[row];
  }

  f32x16 a00, a01, a10, a11;
#pragma unroll
  for (int r = 0; r < 16; ++r) { a00[r] = 0.f; a01[r] = 0.f; a10[r] = 0.f; a11[r] = 0.f; }
  float mn[32];
#pragma unroll
  for (int sl = 0; sl < 32; ++sl) mn[sl] = INFINITY;
  u32 idp[8] = {0, 0, 0, 0, 0, 0, 0, 0};
  float cnv0 = 0.f, cnv1 = 0.f;

  // ---- main loop: 16 code tiles x 16 k-steps; NO barriers, per-wave dbuf
#pragma unroll 1
  for (int ct = 0; ct < 16; ++ct) {
#pragma unroll
    for (int ks = 0; ks < 16; ++ks) {
      const int st = (ct << 4) + ks;
      if (ks == 0) {                       // issued before glls -> drained by wait
        cnv0 = cn[(ct << 9) + (w << 6) + col];
        cnv1 = cn[(ct << 9) + (w << 6) + 32 + col];
      }
      const bool more = (ct < 15) || (ks < 15);
      if (more) {                          // prefetch stage(st+1), stays in flight
        const _Float16* src = W + ((size_t)(st + 1) << 14) + chunk + (lane << 3);
        _Float16* dst = &Bsh[(st + 1) & 1][chunk];
#pragma unroll
        for (int i = 0; i < 4; ++i) gll16(src + (i << 9), dst + (i << 9));
      }
      if (more) asm volatile("s_waitcnt vmcnt(4)" ::: "memory");  // stage(st) done
      else      asm volatile("s_waitcnt vmcnt(0)" ::: "memory");
      __builtin_amdgcn_sched_barrier(0);

      const int ko = (ks << 4) + (hi << 3);
      const v8h ah0 = *(const v8h*)&F2[0][col][ko];
      const v8h ah1 = *(const v8h*)&F2[0][32 + col][ko];
      const v8h am0 = *(const v8h*)&F2[1][col][ko];
      const v8h am1 = *(const v8h*)&F2[1][32 + col][ko];
      const _Float16* Bb = Bsh[st & 1];
      const v8h bh0 = *(const v8h*)&Bb[rb0];
      const v8h bh1 = *(const v8h*)&Bb[rb0 + 256];
      const v8h bm0 = *(const v8h*)&Bb[rb0 + 1024];
      const v8h bm1 = *(const v8h*)&Bb[rb0 + 1280];

      a00 = MFMA16(ah0, bh0, a00, 0, 0, 0);
      a01 = MFMA16(ah0, bh1, a01, 0, 0, 0);
      a10 = MFMA16(ah1, bh0, a10, 0, 0, 0);
      a11 = MFMA16(ah1, bh1, a11, 0, 0, 0);
      a00 = MFMA16(ah0, bm0, a00, 0, 0, 0);
      a01 = MFMA16(ah0, bm1, a01, 0, 0, 0);
      a10 = MFMA16(ah1, bm0, a10, 0, 0, 0);
      a11 = MFMA16(ah1, bm1, a11, 0, 0, 0);
      a00 = MFMA16(am0, bh0, a00, 0, 0, 0);
      a01 = MFMA16(am0, bh1, a01, 0, 0, 0);
      a10 = MFMA16(am1, bh0, a10, 0, 0, 0);
      a11 = MFMA16(am1, bh1, a11, 0, 0, 0);
    }
    // ---- tile epilogue: s = (fn - 2*dot) + cn, running argmin
#pragma unroll
    for (int sl = 0; sl < 32; ++sl) {
      const int Mb = sl >> 4, reg = sl & 15;
      const float base = fnr[sl];
      const u32 sh = (u32)((sl & 3) << 3);
      const float d0 = (Mb == 0) ? a00[reg] : a10[reg];
      const float d1 = (Mb == 0) ? a01[reg] : a11[reg];
      {
        float s = (base + (-0x1p-25f) * d0) + cnv0;
        const bool better = s < mn[sl];
        const u32 curv = idp[sl >> 2];
        const u32 upd = (curv & ~(255u << sh)) | (((u32)(ct << 1)) << sh);
        idp[sl >> 2] = better ? upd : curv;
        mn[sl] = better ? s : mn[sl];
      }
      {
        float s = (base + (-0x1p-25f) * d1) + cnv1;
        const bool better = s < mn[sl];
        const u32 curv = idp[sl >> 2];
        const u32 upd = (curv & ~(255u << sh)) | (((u32)((ct << 1) | 1)) << sh);
        idp[sl >> 2] = better ? upd : curv;
        mn[sl] = better ? s : mn[sl];
      }
    }
#pragma unroll
    for (int r = 0; r < 16; ++r) { a00[r] = 0.f; a01[r] = 0.f; a10[r] = 0.f; a11[r] = 0.f; }
  }

  // ---- final reduction: per-slot butterfly over 32 col-lanes, then cross-wave
#pragma unroll
  for (int sl = 0; sl < 32; ++sl) {
    float v = mn[sl];
    const u32 byte = (idp[sl >> 2] >> ((sl & 3) << 3)) & 255u;
    u32 code = ((byte >> 1) << 9) + ((u32)w << 6) + ((byte & 1) << 5) + (u32)col;
#pragma unroll
    for (int off = 1; off < 32; off <<= 1) {
      float v2 = __shfl_xor(v, off, 64);
      u32 c2 = (u32)__shfl_xor((int)code, off, 64);
      if (v2 < v || (v2 == v && c2 < code)) { v = v2; code = c2; }
    }
    if (col == 0) {
      const int row = ((sl >> 4) << 5) + (sl & 3) + (((sl >> 2) & 3) << 3) + (hi << 2);
      wredS[w][row] = v; wredC[w][row] = code;
    }
  }
  __syncthreads();
  if (tid < 64) {
    float bv = wredS[0][tid]; u32 bc = wredC[0][tid];
#pragma unroll
    for (int j = 1; j < 8; ++j) {
      float vv = wredS[j][tid]; u32 cc = wredC[j][tid];
      if (vv < bv || (vv == bv && cc < bc)) { bv = vv; bc = cc; }
    }
    finS[tid] = bc;
    out[(size_t)8388608 + ((size_t)b << 10) + (h0 << 5) + tid] = (float)bc;
  }
  __syncthreads();

  // ---- codes gather: out[b,c,h,w] = codebook[idx][c]
  {
    const int pt = tid & 63, cg = tid >> 6;
    const u32 code = finS[pt];
    const float4* cbr = cb4 + ((size_t)code << 6);
    const size_t obase = ((size_t)b << 18) + (h0 << 5) + pt;
#pragma unroll
    for (int cc = 0; cc < 8; ++cc) {
      const int c4 = (cc << 3) + cg;
      float4 vv = cbr[c4];
      out[obase + (size_t)((c4 << 2) + 0) * 1024] = vv.x;
      out[obase + (size_t)((c4 << 2) + 1) * 1024] = vv.y;
      out[obase + (size_t)((c4 << 2) + 2) * 1024] = vv.z;
      out[obase + (size_t)((c4 << 2) + 3) * 1024] = vv.w;
    }
  }
}

// ---------------- fallback (round-3 kernel, used only if ws too small) -------
__global__ void __launch_bounds__(512, 2) vq_fb(const float* __restrict__ x,
                                                const float4* __restrict__ cb4,
                                                const float* __restrict__ cn,
                                                float* __restrict__ out) {
  __shared__ __align__(16) _Float16 F2[2][64][264];
  __shared__ __align__(16) _Float16 Bsh[512][72];
  __shared__ float fnP[64][8];
  __shared__ float fnS[64];
  __shared__ float wredS[8][64];
  __shared__ u32  wredC[8][64];
  __shared__ u32  finS[64];

  const int tid = threadIdx.x;
  const int lane = tid & 63;
  const int w = tid >> 6;
  const int col = lane & 31;
  const int hi = lane >> 5;
  const int b = blockIdx.x >> 4;
  const int h0 = (blockIdx.x & 15) << 1;

  float4 rg[8];
  {
    const float4* src = cb4 + ((size_t)tid << 6);
#pragma unroll
    for (int j = 0; j < 8; ++j) rg[j] = src[j];
  }
  {
    const float* xb = x + ((size_t)b << 18) + (h0 << 5);
    float s = 0.f;
#pragma unroll
    for (int j = 0; j < 4; ++j) {
      v8h hv, mv;
#pragma unroll
      for (int i = 0; i < 8; ++i) {
        const int c = (w << 5) + (j << 3) + i;
        float v = xb[(size_t)c * 1024 + lane];
        s += v * v;
        float vs = v * 8192.f;
        _Float16 h = (_Float16)vs;
        _Float16 m = (_Float16)(vs - (float)h);
        hv[i] = h; mv[i] = m;
      }
      *(v8h*)&F2[0][lane][(w << 5) + (j << 3)] = hv;
      *(v8h*)&F2[1][lane][(w << 5) + (j << 3)] = mv;
    }
    fnP[lane][w] = s;
  }
  __syncthreads();
  if (tid < 64) {
    float t = 0.f;
#pragma unroll
    for (int j = 0; j < 8; ++j) t += fnP[tid][j];
    fnS[tid] = t;
  }
  {
#pragma unroll
    for (int j = 0; j < 4; ++j) {
      float t0[8] = {rg[2*j].x, rg[2*j].y, rg[2*j].z, rg[2*j].w,
                     rg[2*j+1].x, rg[2*j+1].y, rg[2*j+1].z, rg[2*j+1].w};
      v8h hv, mv;
#pragma unroll
      for (int i = 0; i < 8; ++i) {
        float vs = t0[i] * 8192.f;
        _Float16 h = (_Float16)vs;
        _Float16 m = (_Float16)(vs - (float)h);
        hv[i] = h; mv[i] = m;
      }
      *(v8h*)&Bsh[tid][(j << 3)] = hv;
      *(v8h*)&Bsh[tid][32 + (j << 3)] = mv;
    }
  }
  __syncthreads();

  float fnr[32];
#pragma unroll
  for (int sl = 0; sl < 32; ++sl) {
    const int row = ((sl >> 4) << 5) + (sl & 3) + (((sl >> 2) & 3) << 3) + (hi << 2);
    fnr[sl] = fnS[row];
  }

  f32x16 acc[2][2];
#pragma unroll
  for (int r = 0; r < 16; ++r) {
    acc[0][0][r] = 0.f; acc[0][1][r] = 0.f; acc[1][0][r] = 0.f; acc[1][1][r] = 0.f;
  }
  float mn[32];
#pragma unroll
  for (int sl = 0; sl < 32; ++sl) mn[sl] = INFINITY;
  u32 idp[8] = {0, 0, 0, 0, 0, 0, 0, 0};
  float cnv0 = 0.f, cnv1 = 0.f;

  for (int st = 0; st < 128; ++st) {
    const int ks = st & 7, ct = st >> 3;
    if (st < 127) {
      const int tn = st + 1;
      const float4* src = cb4 + ((size_t)((((tn >> 3) << 9) + tid)) << 6) + ((tn & 7) << 3);
#pragma unroll
      for (int j = 0; j < 8; ++j) rg[j] = src[j];
    }
    if (ks == 0) {
      cnv0 = cn[(ct << 9) + (w << 6) + col];
      cnv1 = cn[(ct << 9) + (w << 6) + 32 + col];
    }
    const int kb = ks << 5;
#pragma unroll
    for (int kh = 0; kh < 2; ++kh) {
      const int ko = kb + (kh << 4) + (hi << 3);
      const v8h ah0 = *(const v8h*)&F2[0][col][ko];
      const v8h ah1 = *(const v8h*)&F2[0][32 + col][ko];
      const v8h am0 = *(const v8h*)&F2[1][col][ko];
      const v8h am1 = *(const v8h*)&F2[1][32 + col][ko];
      const int bo = (kh << 4) + (hi << 3);
      const v8h bh0 = *(const v8h*)&Bsh[(w << 6) + col][bo];
      const v8h bh1 = *(const v8h*)&Bsh[(w << 6) + 32 + col][bo];
      const v8h bm0 = *(const v8h*)&Bsh[(w << 6) + col][32 + bo];
      const v8h bm1 = *(const v8h*)&Bsh[(w << 6) + 32 + col][32 + bo];
      acc[0][0] = MFMA16(ah0, bh0, acc[0][0], 0, 0, 0);
      acc[0][0] = MFMA16(ah0, bm0, acc[0][0], 0, 0, 0);
      acc[0][0] = MFMA16(am0, bh0, acc[0][0], 0, 0, 0);
      acc[0][1] = MFMA16(ah0, bh1, acc[0][1], 0, 0, 0);
      acc[0][1] = MFMA16(ah0, bm1, acc[0][1], 0, 0, 0);
      acc[0][1] = MFMA16(am0, bh1, acc[0][1], 0, 0, 0);
      acc[1][0] = MFMA16(ah1, bh0, acc[1][0], 0, 0, 0);
      acc[1][0] = MFMA16(ah1, bm0, acc[1][0], 0, 0, 0);
      acc[1][0] = MFMA16(am1, bh0, acc[1][0], 0, 0, 0);
      acc[1][1] = MFMA16(ah1, bh1, acc[1][1], 0, 0, 0);
      acc[1][1] = MFMA16(ah1, bm1, acc[1][1], 0, 0, 0);
      acc[1][1] = MFMA16(am1, bh1, acc[1][1], 0, 0, 0);
    }
    if (ks == 7) {
#pragma unroll
      for (int sl = 0; sl < 32; ++sl) {
        const int Mb = sl >> 4, reg = sl & 15;
        const float base = fnr[sl];
        const u32 sh = (u32)((sl & 3) << 3);
        {
          float s = (base + (-0x1p-25f) * acc[Mb][0][reg]) + cnv0;
          const bool better = s < mn[sl];
          const u32 curv = idp[sl >> 2];
          const u32 upd = (curv & ~(255u << sh)) | (((u32)(ct << 1)) << sh);
          idp[sl >> 2] = better ? upd : curv;
          mn[sl] = better ? s : mn[sl];
        }
        {
          float s = (base + (-0x1p-25f) * acc[Mb][1][reg]) + cnv1;
          const bool better = s < mn[sl];
          const u32 curv = idp[sl >> 2];
          const u32 upd = (curv & ~(255u << sh)) | (((u32)((ct << 1) | 1)) << sh);
          idp[sl >> 2] = better ? upd : curv;
          mn[sl] = better ? s : mn[sl];
        }
      }
#pragma unroll
      for (int r = 0; r < 16; ++r) {
        acc[0][0][r] = 0.f; acc[0][1][r] = 0.f; acc[1][0][r] = 0.f; acc[1][1][r] = 0.f;
      }
    }
    v8h cr[8];
    if (st < 127) {
#pragma unroll
      for (int j = 0; j < 4; ++j) {
        float t0[8] = {rg[2*j].x, rg[2*j].y, rg[2*j].z, rg[2*j].w,
                       rg[2*j+1].x, rg[2*j+1].y, rg[2*j+1].z, rg[2*j+1].w};
#pragma unroll
        for (int i = 0; i < 8; ++i) {
          float vs = t0[i] * 8192.f;
          _Float16 h = (_Float16)vs;
          _Float16 m = (_Float16)(vs - (float)h);
          cr[j][i] = h; cr[4 + j][i] = m;
        }
      }
    }
    __syncthreads();
    if (st < 127) {
#pragma unroll
      for (int j = 0; j < 4; ++j) {
        *(v8h*)&Bsh[tid][(j << 3)] = cr[j];
        *(v8h*)&Bsh[tid][32 + (j << 3)] = cr[4 + j];
      }
    }
    __syncthreads();
  }

#pragma unroll
  for (int sl = 0; sl < 32; ++sl) {
    float v = mn[sl];
    const u32 byte = (idp[sl >> 2] >> ((sl & 3) << 3)) & 255u;
    u32 code = ((byte >> 1) << 9) + ((u32)w << 6) + ((byte & 1) << 5) + (u32)col;
#pragma unroll
    for (int off = 1; off < 32; off <<= 1) {
      float v2 = __shfl_xor(v, off, 64);
      u32 c2 = (u32)__shfl_xor((int)code, off, 64);
      if (v2 < v || (v2 == v && c2 < code)) { v = v2; code = c2; }
    }
    if (col == 0) {
      const int row = ((sl >> 4) << 5) + (sl & 3) + (((sl >> 2) & 3) << 3) + (hi << 2);
      wredS[w][row] = v; wredC[w][row] = code;
    }
  }
  __syncthreads();
  if (tid < 64) {
    float bv = wredS[0][tid]; u32 bc = wredC[0][tid];
#pragma unroll
    for (int j = 1; j < 8; ++j) {
      float vv = wredS[j][tid]; u32 cc = wredC[j][tid];
      if (vv < bv || (vv == bv && cc < bc)) { bv = vv; bc = cc; }
    }
    finS[tid] = bc;
    out[(size_t)8388608 + ((size_t)b << 10) + (h0 << 5) + tid] = (float)bc;
  }
  __syncthreads();
  {
    const int pt = tid & 63, cg = tid >> 6;
    const u32 code = finS[pt];
    const float4* cbr = cb4 + ((size_t)code << 6);
    const size_t obase = ((size_t)b << 18) + (h0 << 5) + pt;
#pragma unroll
    for (int cc = 0; cc < 8; ++cc) {
      const int c4 = (cc << 3) + cg;
      float4 vv = cbr[c4];
      out[obase + (size_t)((c4 << 2) + 0) * 1024] = vv.x;
      out[obase + (size_t)((c4 << 2) + 1) * 1024] = vv.y;
      out[obase + (size_t)((c4 << 2) + 2) * 1024] = vv.z;
      out[obase + (size_t)((c4 << 2) + 3) * 1024] = vv.w;
    }
  }
}

extern "C" void kernel_launch(void* const* d_in, const int* in_sizes, int n_in,
                              void* d_out, int out_size, void* d_ws, size_t ws_size,
                              hipStream_t stream) {
  const float* x = (const float*)d_in[0];
  const float* cb = (const float*)d_in[1];
  float* out = (float*)d_out;
  float* cnorm = (float*)d_ws;  // 8192 floats at ws[0:32KB)

  cnorm_k<<<2048, 256, 0, stream>>>((const float4*)cb, cnorm);
  if (ws_size >= (size_t)32768 + (size_t)16777216) {
    _Float16* W = (_Float16*)((char*)d_ws + 32768);  // 16 MB split-permuted planes
    split_cb<<<1024, 256, 0, stream>>>((const float4*)cb, W);
    vq_fast<<<512, 512, 0, stream>>>(x, (const float4*)cb, cnorm, W, out);
  } else {
    vq_fb<<<512, 512, 0, stream>>>(x, (const float4*)cb, cnorm, out);
  }
}

// Round 7
// 440.269 us; speedup vs baseline: 1.6394x; 1.0019x over previous
//
#include <hip/hip_runtime.h>
#include <math.h>

// VQ via split-fp16 MFMA emulation of fp32 GEMM.
// Round 7: 64x128 wave tile (2x4 fragments). Half-step pipeline: 12 MFMA per
// 4 B-frag reads; A-frags read once per full-step (reused across N-halves).
// Per-wave-private B staging via global_load_lds, counted vmcnt(4), no barriers.
// LDS/MFMA = 0.5 KB (was 0.667). MFMA per-chain order preserved bit-identically.
// x [32,256,32,32] f32, codebook [8192,256] f32.
// d2 = (||f||^2 - 2 f.c) + ||c||^2, argmin over 8192 codes, np association.
// f.c = 2^-26 * MFMA(h/m split of 8192*f, 8192*c): products hh+hm+mh.
// Outputs: codes [32,256,32,32] f32 then indices [32,32,32] (as float).

typedef _Float16 v8h __attribute__((ext_vector_type(8)));
typedef float f32x16 __attribute__((ext_vector_type(16)));
typedef unsigned int u32;

#define MFMA16 __builtin_amdgcn_mfma_f32_32x32x16_f16

__device__ __forceinline__ void gll16(const _Float16* g, _Float16* l) {
  __builtin_amdgcn_global_load_lds(
      (const __attribute__((address_space(1))) void*)(const void*)g,
      (__attribute__((address_space(3))) void*)(void*)l, 16, 0, 0);
}

__global__ __launch_bounds__(256) void cnorm_k(const float4* __restrict__ cb4,
                                               float* __restrict__ cn) {
  int lane = threadIdx.x & 63;
  int row = (blockIdx.x << 2) + (threadIdx.x >> 6);
  float4 v = cb4[(size_t)row * 64 + lane];
  float s = v.x * v.x + v.y * v.y + v.z * v.z + v.w * v.w;
#pragma unroll
  for (int off = 32; off > 0; off >>= 1) s += __shfl_xor(s, off, 64);
  if (lane == 0) cn[row] = s;
}

// Pre-split codebook into h/m fp16 planes. Granule g = (ct*16+ks)*2 + half =
// 32 KB = [w(8)][pl(2)][hi(2)][c64(64)][8]; wave half-chunk = 2048 halves.
// value = plane of 8192*cb[ct*1024 + w*128 + half*64 + c64][ks*16 + hi*8 + i].
__global__ __launch_bounds__(256) void split_cb(const float4* __restrict__ cb4,
                                                _Float16* __restrict__ W) {
  const int j = threadIdx.x & 31;
  const int ks = j >> 1, hi = j & 1;
  const int r = (blockIdx.x << 3) + (threadIdx.x >> 5);  // code row 0..8191
  const float4* src = cb4 + (size_t)r * 64 + (ks << 2) + (hi << 1);
  float4 v0 = src[0], v1 = src[1];
  float t[8] = {v0.x, v0.y, v0.z, v0.w, v1.x, v1.y, v1.z, v1.w};
  v8h hv, mv;
#pragma unroll
  for (int i = 0; i < 8; ++i) {
    float vs = t[i] * 8192.f;
    _Float16 h = (_Float16)vs;
    _Float16 m = (_Float16)(vs - (float)h);
    hv[i] = h; mv[i] = m;
  }
  const int ct = r >> 10, wv = (r >> 7) & 7, half = (r >> 6) & 1, c64 = r & 63;
  const int g = (((ct << 4) + ks) << 1) + half;
  _Float16* base = W + ((size_t)g << 14) + (wv << 11);
  *(v8h*)(base + (((hi << 6) + c64) << 3)) = hv;               // pl=0
  *(v8h*)(base + ((128 + (hi << 6) + c64) << 3)) = mv;         // pl=1
}

__global__ void __launch_bounds__(512, 1) vq_fast(const float* __restrict__ x,
                                                  const float4* __restrict__ cb4,
                                                  const float* __restrict__ cn,
                                                  const _Float16* __restrict__ W,
                                                  float* __restrict__ out) {
  __shared__ __align__(16) _Float16 F2[2][64][264];   // 67,584 B: -2x splits, padded
  __shared__ __align__(16) _Float16 Bsh[2][8][2048];  // 65,536 B: 2 bufs x 8 waves x 4KB
  __shared__ float fnP[64][8];
  __shared__ float fnS[64];
  __shared__ float wredS[8][64];
  __shared__ u32  wredC[8][64];
  __shared__ u32  finS[64];

  const int tid = threadIdx.x;
  const int lane = tid & 63;
  const int w = tid >> 6;
  const int col = lane & 31;
  const int hi = lane >> 5;
  const int b = blockIdx.x >> 4;
  const int h0 = (blockIdx.x & 15) << 1;

  // ---- pipeline prologue: stage granules 0,1 (drained by the barriers below)
  {
    const _Float16* s0 = W + (w << 11) + (lane << 3);
    const _Float16* s1 = W + 16384 + (w << 11) + (lane << 3);
#pragma unroll
    for (int k = 0; k < 4; ++k) gll16(s0 + (k << 9), &Bsh[0][w][k << 9]);
#pragma unroll
    for (int k = 0; k < 4; ++k) gll16(s1 + (k << 9), &Bsh[1][w][k << 9]);
  }

  // ---- stage F splits (scaled by 2^13) + fn partials
  {
    const float* xb = x + ((size_t)b << 18) + (h0 << 5);
    float s = 0.f;
#pragma unroll
    for (int j = 0; j < 4; ++j) {
      v8h hv, mv;
#pragma unroll
      for (int i = 0; i < 8; ++i) {
        const int c = (w << 5) + (j << 3) + i;
        float v = xb[(size_t)c * 1024 + lane];   // coalesced: lane = point
        s += v * v;
        float vs = v * 8192.f;
        _Float16 h = (_Float16)vs;
        _Float16 m = (_Float16)(vs - (float)h);
        hv[i] = h; mv[i] = m;
      }
      *(v8h*)&F2[0][lane][(w << 5) + (j << 3)] = hv;
      *(v8h*)&F2[1][lane][(w << 5) + (j << 3)] = mv;
    }
    fnP[lane][w] = s;
  }
  __syncthreads();   // F2 + fnP visible; prologue glls drained
  if (tid < 64) {
    float t = 0.f;
#pragma unroll
    for (int j = 0; j < 8; ++j) t += fnP[tid][j];
    fnS[tid] = t;
  }
  __syncthreads();   // fnS visible — last barrier before the final reductions

  f32x16 acc[2][4];
#pragma unroll
  for (int n = 0; n < 4; ++n)
#pragma unroll
    for (int r = 0; r < 16; ++r) { acc[0][n][r] = 0.f; acc[1][n][r] = 0.f; }
  float mn[32];
#pragma unroll
  for (int sl = 0; sl < 32; ++sl) mn[sl] = INFINITY;
  u32 idp[8] = {0, 0, 0, 0, 0, 0, 0, 0};

  // ---- main loop: 8 code tiles (1024 codes) x 32 half-steps; no barriers
#pragma unroll 1
  for (int ct = 0; ct < 8; ++ct) {
    float cnv[4];
#pragma unroll
    for (int n = 0; n < 4; ++n)        // drained by the in-order vmcnt(4)s below
      cnv[n] = cn[(ct << 10) + (w << 7) + (n << 5) + col];
    v8h ah0, ah1, am0, am1;
#pragma unroll
    for (int hh = 0; hh < 32; ++hh) {
      const int h = (ct << 5) + hh;
      const int ks = hh >> 1, nh = hh & 1;
      // (1) frag ds_reads (stage(h) completion ensured by previous (5))
      if (nh == 0) {
        const int ko = (ks << 4) + (hi << 3);
        ah0 = *(const v8h*)&F2[0][col][ko];
        ah1 = *(const v8h*)&F2[0][32 + col][ko];
        am0 = *(const v8h*)&F2[1][col][ko];
        am1 = *(const v8h*)&F2[1][32 + col][ko];
      }
      const _Float16* Bb = &Bsh[h & 1][w][0];
      const int rb = ((hi << 6) + col) << 3;
      const v8h bh0 = *(const v8h*)&Bb[rb];
      const v8h bh1 = *(const v8h*)&Bb[rb + 256];
      const v8h bm0 = *(const v8h*)&Bb[rb + 1024];
      const v8h bm1 = *(const v8h*)&Bb[rb + 1280];
      // (2) frags must be in regs before stage(h+2) overwrites this buffer
      asm volatile("s_waitcnt lgkmcnt(0)" ::: "memory");
      __builtin_amdgcn_sched_barrier(0);
      // (3) stage granule h+2 into buf[h&1] (just-read buffer)
      if (h + 2 < 256) {
        const _Float16* src = W + ((size_t)(h + 2) << 14) + (w << 11) + (lane << 3);
#pragma unroll
        for (int k = 0; k < 4; ++k) gll16(src + (k << 9), &Bsh[h & 1][w][k << 9]);
      }
      // (4) 12 MFMAs; per-chain order hh,hm,mh with ks ascending (bit-identical)
      const int n0 = nh << 1, n1 = n0 + 1;
      acc[0][n0] = MFMA16(ah0, bh0, acc[0][n0], 0, 0, 0);
      acc[0][n1] = MFMA16(ah0, bh1, acc[0][n1], 0, 0, 0);
      acc[1][n0] = MFMA16(ah1, bh0, acc[1][n0], 0, 0, 0);
      acc[1][n1] = MFMA16(ah1, bh1, acc[1][n1], 0, 0, 0);
      acc[0][n0] = MFMA16(ah0, bm0, acc[0][n0], 0, 0, 0);
      acc[0][n1] = MFMA16(ah0, bm1, acc[0][n1], 0, 0, 0);
      acc[1][n0] = MFMA16(ah1, bm0, acc[1][n0], 0, 0, 0);
      acc[1][n1] = MFMA16(ah1, bm1, acc[1][n1], 0, 0, 0);
      acc[0][n0] = MFMA16(am0, bh0, acc[0][n0], 0, 0, 0);
      acc[0][n1] = MFMA16(am0, bh1, acc[0][n1], 0, 0, 0);
      acc[1][n0] = MFMA16(am1, bh0, acc[1][n0], 0, 0, 0);
      acc[1][n1] = MFMA16(am1, bh1, acc[1][n1], 0, 0, 0);
      // (5) ensure stage(h+1) complete (in-order retirement; cnv loads retire too)
      if (h < 254) asm volatile("s_waitcnt vmcnt(4)" ::: "memory");
      else         asm volatile("s_waitcnt vmcnt(0)" ::: "memory");
      __builtin_amdgcn_sched_barrier(0);
    }
    // ---- tile epilogue: s = (fn - 2*dot) + cn, running argmin over 4 N-blocks
#pragma unroll
    for (int sl = 0; sl < 32; ++sl) {
      const int Mb = sl >> 4, reg = sl & 15;
      const int row = ((sl >> 4) << 5) + (sl & 3) + (((sl >> 2) & 3) << 3) + (hi << 2);
      const float base = fnS[row];
      const u32 sh = (u32)((sl & 3) << 3);
#pragma unroll
      for (int n = 0; n < 4; ++n) {
        const float d = (Mb == 0) ? acc[0][n][reg] : acc[1][n][reg];
        float s = (base + (-0x1p-25f) * d) + cnv[n];
        const bool better = s < mn[sl];
        const u32 curv = idp[sl >> 2];
        const u32 upd = (curv & ~(255u << sh)) | (((u32)((ct << 2) + n)) << sh);
        idp[sl >> 2] = better ? upd : curv;
        mn[sl] = better ? s : mn[sl];
      }
    }
#pragma unroll
    for (int n = 0; n < 4; ++n)
#pragma unroll
      for (int r = 0; r < 16; ++r) { acc[0][n][r] = 0.f; acc[1][n][r] = 0.f; }
  }

  // ---- final reduction: per-slot butterfly over 32 col-lanes, then cross-wave
#pragma unroll
  for (int sl = 0; sl < 32; ++sl) {
    float v = mn[sl];
    const u32 byte = (idp[sl >> 2] >> ((sl & 3) << 3)) & 255u;
    u32 code = ((byte >> 2) << 10) + ((u32)w << 7) + ((byte & 3) << 5) + (u32)col;
#pragma unroll
    for (int off = 1; off < 32; off <<= 1) {
      float v2 = __shfl_xor(v, off, 64);
      u32 c2 = (u32)__shfl_xor((int)code, off, 64);
      if (v2 < v || (v2 == v && c2 < code)) { v = v2; code = c2; }
    }
    if (col == 0) {
      const int row = ((sl >> 4) << 5) + (sl & 3) + (((sl >> 2) & 3) << 3) + (hi << 2);
      wredS[w][row] = v; wredC[w][row] = code;
    }
  }
  __syncthreads();
  if (tid < 64) {
    float bv = wredS[0][tid]; u32 bc = wredC[0][tid];
#pragma unroll
    for (int j = 1; j < 8; ++j) {
      float vv = wredS[j][tid]; u32 cc = wredC[j][tid];
      if (vv < bv || (vv == bv && cc < bc)) { bv = vv; bc = cc; }
    }
    finS[tid] = bc;
    out[(size_t)8388608 + ((size_t)b << 10) + (h0 << 5) + tid] = (float)bc;
  }
  __syncthreads();

  // ---- codes gather: out[b,c,h,w] = codebook[idx][c]
  {
    const int pt = tid & 63, cg = tid >> 6;
    const u32 code = finS[pt];
    const float4* cbr = cb4 + ((size_t)code << 6);
    const size_t obase = ((size_t)b << 18) + (h0 << 5) + pt;
#pragma unroll
    for (int cc = 0; cc < 8; ++cc) {
      const int c4 = (cc << 3) + cg;
      float4 vv = cbr[c4];
      out[obase + (size_t)((c4 << 2) + 0) * 1024] = vv.x;
      out[obase + (size_t)((c4 << 2) + 1) * 1024] = vv.y;
      out[obase + (size_t)((c4 << 2) + 2) * 1024] = vv.z;
      out[obase + (size_t)((c4 << 2) + 3) * 1024] = vv.w;
    }
  }
}

// ---------------- fallback (round-3 kernel, used only if ws too small) -------
__global__ void __launch_bounds__(512, 2) vq_fb(const float* __restrict__ x,
                                                const float4* __restrict__ cb4,
                                                const float* __restrict__ cn,
                                                float* __restrict__ out) {
  __shared__ __align__(16) _Float16 F2[2][64][264];
  __shared__ __align__(16) _Float16 Bsh[512][72];
  __shared__ float fnP[64][8];
  __shared__ float fnS[64];
  __shared__ float wredS[8][64];
  __shared__ u32  wredC[8][64];
  __shared__ u32  finS[64];

  const int tid = threadIdx.x;
  const int lane = tid & 63;
  const int w = tid >> 6;
  const int col = lane & 31;
  const int hi = lane >> 5;
  const int b = blockIdx.x >> 4;
  const int h0 = (blockIdx.x & 15) << 1;

  float4 rg[8];
  {
    const float4* src = cb4 + ((size_t)tid << 6);
#pragma unroll
    for (int j = 0; j < 8; ++j) rg[j] = src[j];
  }
  {
    const float* xb = x + ((size_t)b << 18) + (h0 << 5);
    float s = 0.f;
#pragma unroll
    for (int j = 0; j < 4; ++j) {
      v8h hv, mv;
#pragma unroll
      for (int i = 0; i < 8; ++i) {
        const int c = (w << 5) + (j << 3) + i;
        float v = xb[(size_t)c * 1024 + lane];
        s += v * v;
        float vs = v * 8192.f;
        _Float16 h = (_Float16)vs;
        _Float16 m = (_Float16)(vs - (float)h);
        hv[i] = h; mv[i] = m;
      }
      *(v8h*)&F2[0][lane][(w << 5) + (j << 3)] = hv;
      *(v8h*)&F2[1][lane][(w << 5) + (j << 3)] = mv;
    }
    fnP[lane][w] = s;
  }
  __syncthreads();
  if (tid < 64) {
    float t = 0.f;
#pragma unroll
    for (int j = 0; j < 8; ++j) t += fnP[tid][j];
    fnS[tid] = t;
  }
  {
#pragma unroll
    for (int j = 0; j < 4; ++j) {
      float t0[8] = {rg[2*j].x, rg[2*j].y, rg[2*j].z, rg[2*j].w,
                     rg[2*j+1].x, rg[2*j+1].y, rg[2*j+1].z, rg[2*j+1].w};
      v8h hv, mv;
#pragma unroll
      for (int i = 0; i < 8; ++i) {
        float vs = t0[i] * 8192.f;
        _Float16 h = (_Float16)vs;
        _Float16 m = (_Float16)(vs - (float)h);
        hv[i] = h; mv[i] = m;
      }
      *(v8h*)&Bsh[tid][(j << 3)] = hv;
      *(v8h*)&Bsh[tid][32 + (j << 3)] = mv;
    }
  }
  __syncthreads();

  float fnr[32];
#pragma unroll
  for (int sl = 0; sl < 32; ++sl) {
    const int row = ((sl >> 4) << 5) + (sl & 3) + (((sl >> 2) & 3) << 3) + (hi << 2);
    fnr[sl] = fnS[row];
  }

  f32x16 acc[2][2];
#pragma unroll
  for (int r = 0; r < 16; ++r) {
    acc[0][0][r] = 0.f; acc[0][1][r] = 0.f; acc[1][0][r] = 0.f; acc[1][1][r] = 0.f;
  }
  float mn[32];
#pragma unroll
  for (int sl = 0; sl < 32; ++sl) mn[sl] = INFINITY;
  u32 idp[8] = {0, 0, 0, 0, 0, 0, 0, 0};
  float cnv0 = 0.f, cnv1 = 0.f;

  for (int st = 0; st < 128; ++st) {
    const int ks = st & 7, ct = st >> 3;
    if (st < 127) {
      const int tn = st + 1;
      const float4* src = cb4 + ((size_t)((((tn >> 3) << 9) + tid)) << 6) + ((tn & 7) << 3);
#pragma unroll
      for (int j = 0; j < 8; ++j) rg[j] = src[j];
    }
    if (ks == 0) {
      cnv0 = cn[(ct << 9) + (w << 6) + col];
      cnv1 = cn[(ct << 9) + (w << 6) + 32 + col];
    }
    const int kb = ks << 5;
#pragma unroll
    for (int kh = 0; kh < 2; ++kh) {
      const int ko = kb + (kh << 4) + (hi << 3);
      const v8h ah0 = *(const v8h*)&F2[0][col][ko];
      const v8h ah1 = *(const v8h*)&F2[0][32 + col][ko];
      const v8h am0 = *(const v8h*)&F2[1][col][ko];
      const v8h am1 = *(const v8h*)&F2[1][32 + col][ko];
      const int bo = (kh << 4) + (hi << 3);
      const v8h bh0 = *(const v8h*)&Bsh[(w << 6) + col][bo];
      const v8h bh1 = *(const v8h*)&Bsh[(w << 6) + 32 + col][bo];
      const v8h bm0 = *(const v8h*)&Bsh[(w << 6) + col][32 + bo];
      const v8h bm1 = *(const v8h*)&Bsh[(w << 6) + 32 + col][32 + bo];
      acc[0][0] = MFMA16(ah0, bh0, acc[0][0], 0, 0, 0);
      acc[0][0] = MFMA16(ah0, bm0, acc[0][0], 0, 0, 0);
      acc[0][0] = MFMA16(am0, bh0, acc[0][0], 0, 0, 0);
      acc[0][1] = MFMA16(ah0, bh1, acc[0][1], 0, 0, 0);
      acc[0][1] = MFMA16(ah0, bm1, acc[0][1], 0, 0, 0);
      acc[0][1] = MFMA16(am0, bh1, acc[0][1], 0, 0, 0);
      acc[1][0] = MFMA16(ah1, bh0, acc[1][0], 0, 0, 0);
      acc[1][0] = MFMA16(ah1, bm0, acc[1][0], 0, 0, 0);
      acc[1][0] = MFMA16(am1, bh0, acc[1][0], 0, 0, 0);
      acc[1][1] = MFMA16(ah1, bh1, acc[1][1], 0, 0, 0);
      acc[1][1] = MFMA16(ah1, bm1, acc[1][1], 0, 0, 0);
      acc[1][1] = MFMA16(am1, bh1, acc[1][1], 0, 0, 0);
    }
    if (ks == 7) {
#pragma unroll
      for (int sl = 0; sl < 32; ++sl) {
        const int Mb = sl >> 4, reg = sl & 15;
        const float base = fnr[sl];
        const u32 sh = (u32)((sl & 3) << 3);
        {
          float s = (base + (-0x1p-25f) * acc[Mb][0][reg]) + cnv0;
          const bool better = s < mn[sl];
          const u32 curv = idp[sl >> 2];
          const u32 upd = (curv & ~(255u << sh)) | (((u32)(ct << 1)) << sh);
          idp[sl >> 2] = better ? upd : curv;
          mn[sl] = better ? s : mn[sl];
        }
        {
          float s = (base + (-0x1p-25f) * acc[Mb][1][reg]) + cnv1;
          const bool better = s < mn[sl];
          const u32 curv = idp[sl >> 2];
          const u32 upd = (curv & ~(255u << sh)) | (((u32)((ct << 1) | 1)) << sh);
          idp[sl >> 2] = better ? upd : curv;
          mn[sl] = better ? s : mn[sl];
        }
      }
#pragma unroll
      for (int r = 0; r < 16; ++r) {
        acc[0][0][r] = 0.f; acc[0][1][r] = 0.f; acc[1][0][r] = 0.f; acc[1][1][r] = 0.f;
      }
    }
    v8h cr[8];
    if (st < 127) {
#pragma unroll
      for (int j = 0; j < 4; ++j) {
        float t0[8] = {rg[2*j].x, rg[2*j].y, rg[2*j].z, rg[2*j].w,
                       rg[2*j+1].x, rg[2*j+1].y, rg[2*j+1].z, rg[2*j+1].w};
#pragma unroll
        for (int i = 0; i < 8; ++i) {
          float vs = t0[i] * 8192.f;
          _Float16 h = (_Float16)vs;
          _Float16 m = (_Float16)(vs - (float)h);
          cr[j][i] = h; cr[4 + j][i] = m;
        }
      }
    }
    __syncthreads();
    if (st < 127) {
#pragma unroll
      for (int j = 0; j < 4; ++j) {
        *(v8h*)&Bsh[tid][(j << 3)] = cr[j];
        *(v8h*)&Bsh[tid][32 + (j << 3)] = cr[4 + j];
      }
    }
    __syncthreads();
  }

#pragma unroll
  for (int sl = 0; sl < 32; ++sl) {
    float v = mn[sl];
    const u32 byte = (idp[sl >> 2] >> ((sl & 3) << 3)) & 255u;
    u32 code = ((byte >> 1) << 9) + ((u32)w << 6) + ((byte & 1) << 5) + (u32)col;
#pragma unroll
    for (int off = 1; off < 32; off <<= 1) {
      float v2 = __shfl_xor(v, off, 64);
      u32 c2 = (u32)__shfl_xor((int)code, off, 64);
      if (v2 < v || (v2 == v && c2 < code)) { v = v2; code = c2; }
    }
    if (col == 0) {
      const int row = ((sl >> 4) << 5) + (sl & 3) + (((sl >> 2) & 3) << 3) + (hi << 2);
      wredS[w][row] = v; wredC[w][row] = code;
    }
  }
  __syncthreads();
  if (tid < 64) {
    float bv = wredS[0][tid]; u32 bc = wredC[0][tid];
#pragma unroll
    for (int j = 1; j < 8; ++j) {
      float vv = wredS[j][tid]; u32 cc = wredC[j][tid];
      if (vv < bv || (vv == bv && cc < bc)) { bv = vv; bc = cc; }
    }
    finS[tid] = bc;
    out[(size_t)8388608 + ((size_t)b << 10) + (h0 << 5) + tid] = (float)bc;
  }
  __syncthreads();
  {
    const int pt = tid & 63, cg = tid >> 6;
    const u32 code = finS[pt];
    const float4* cbr = cb4 + ((size_t)code << 6);
    const size_t obase = ((size_t)b << 18) + (h0 << 5) + pt;
#pragma unroll
    for (int cc = 0; cc < 8; ++cc) {
      const int c4 = (cc << 3) + cg;
      float4 vv = cbr[c4];
      out[obase + (size_t)((c4 << 2) + 0) * 1024] = vv.x;
      out[obase + (size_t)((c4 << 2) + 1) * 1024] = vv.y;
      out[obase + (size_t)((c4 << 2) + 2) * 1024] = vv.z;
      out[obase + (size_t)((c4 << 2) + 3) * 1024] = vv.w;
    }
  }
}

extern "C" void kernel_launch(void* const* d_in, const int* in_sizes, int n_in,
                              void* d_out, int out_size, void* d_ws, size_t ws_size,
                              hipStream_t stream) {
  const float* x = (const float*)d_in[0];
  const float* cb = (const float*)d_in[1];
  float* out = (float*)d_out;
  float* cnorm = (float*)d_ws;  // 8192 floats at ws[0:32KB)

  cnorm_k<<<2048, 256, 0, stream>>>((const float4*)cb, cnorm);
  if (ws_size >= (size_t)32768 + (size_t)8388608) {
    _Float16* W = (_Float16*)((char*)d_ws + 32768);  // 8 MB split-permuted planes
    split_cb<<<1024, 256, 0, stream>>>((const float4*)cb, W);
    vq_fast<<<512, 512, 0, stream>>>(x, (const float4*)cb, cnorm, W, out);
  } else {
    vq_fb<<<512, 512, 0, stream>>>(x, (const float4*)cb, cnorm, out);
  }
}